// Round 7
// baseline (121.303 us; speedup 1.0000x reference)
//
#include <hip/hip_runtime.h>

typedef unsigned short ushort_t;
using short8 = __attribute__((ext_vector_type(8))) short;
using half4  = __attribute__((ext_vector_type(4))) _Float16;
using half8  = __attribute__((ext_vector_type(8))) _Float16;
using f32x4  = __attribute__((ext_vector_type(4))) float;

#define AS1 __attribute__((address_space(1)))
#define AS3 __attribute__((address_space(3)))

// Problem sizes (fixed)
#define B_   8
#define S_   2048
#define D_   1024
#define NIN  (8UL * 2048UL * 1024UL)
#define PARTS 32
#define SROWB 8192UL
#define BATCHB (2048UL * SROWB)

// Per-score-row layout during the pipeline:
//   [0,128)     : 32 f32 partial row sums   (gemm -> normalize)
//   [2048,4096) : bf16 X row                (cvt -> gemm)
//   [4096,8192) : f16 E row = exp(logits)   (gemm -> normalize)
// normalize overwrites the whole row with final f32 scores.
// The exact f32 input copy streams through the gemm's idle VMEM slots.

__device__ __forceinline__ ushort_t f2bf(float f) {
    unsigned u = __float_as_uint(f);
    u += 0x7FFFu + ((u >> 16) & 1u);
    return (ushort_t)(u >> 16);
}

// ---------- kernel 1: f32 X -> parked bf16 ----------
__global__ __launch_bounds__(256) void cvt_packed(const float* __restrict__ in,
                                                  char* sc) {
    size_t g = ((size_t)blockIdx.x * 256 + threadIdx.x) * 8;
    const float4* p = (const float4*)(in + g);
    float4 a = p[0], c = p[1];
    short8 r;
    r[0] = (short)f2bf(a.x); r[1] = (short)f2bf(a.y);
    r[2] = (short)f2bf(a.z); r[3] = (short)f2bf(a.w);
    r[4] = (short)f2bf(c.x); r[5] = (short)f2bf(c.y);
    r[6] = (short)f2bf(c.z); r[7] = (short)f2bf(c.w);
    size_t xrow = g >> 10;
    size_t col  = g & 1023;
    char* dst = sc + xrow * SROWB + 2048 + col * 2;
    *(short8*)dst = r;
}

// ---------- kernel 2: symmetric GEMM, ring-2 + frag double-buffer + embedded copy ----------
__global__ __launch_bounds__(256, 2) void gemm_sym4(char* sc,
                                                    const float4* xin,
                                                    float4* xout) {
    __shared__ __align__(16) ushort_t sA[2][128 * 64];
    __shared__ __align__(16) ushort_t sB[2][128 * 64];

    const int lin = blockIdx.x;
    // bijective XCD swizzle: 1088 = 8 * 136
    const int wg  = (lin & 7) * 136 + (lin >> 3);
    const int b   = wg / 136;
    int rem = wg % 136, ti = 0;
    while (rem >= 16 - ti) { rem -= 16 - ti; ++ti; }
    const int tj = ti + rem;
    const int tr = ti * 128, tc = tj * 128;

    char* Sb = sc + (size_t)b * BATCHB;

    const int tid  = threadIdx.x;
    const int lane = tid & 63;
    const int wid  = tid >> 6;
    const int wr = (wid >> 1) * 64;
    const int wc = (wid & 1) * 64;

    const bool docopy = (lin < 1024);
    const size_t cbase = (size_t)lin * 256 + tid;

    f32x4 acc[4][4] = {};
    float4 creg;

    const int srow_s = tid >> 3;
    const int cd     = tid & 7;
    const int rsel = lane & 15;
    const int g4   = lane >> 4;
    const int sw   = lane & 7;

    auto stage = [&](int s, int slot) {
#pragma unroll
        for (int j = 0; j < 4; ++j) {
            const int row = j * 32 + srow_s;
            const int csw = (cd ^ (row & 7)) << 4;
            const size_t rbA = (size_t)(tr + row) * SROWB + 2048 + (size_t)s * 128;
            const size_t rbB = (size_t)(tc + row) * SROWB + 2048 + (size_t)s * 128;
            __builtin_amdgcn_global_load_lds((const AS1 void*)(Sb + rbA + csw),
                (AS3 void*)((char*)&sA[slot][0] + j * 4096 + tid * 16), 16, 0, 0);
            __builtin_amdgcn_global_load_lds((const AS1 void*)(Sb + rbB + csw),
                (AS3 void*)((char*)&sB[slot][0] + j * 4096 + tid * 16), 16, 0, 0);
        }
    };

    // frag double-buffer: F[fb][kk][m] — fb,kk,m all compile-time after unroll
    short8 af[2][2][4], bfr[2][2][4];

    auto readfrags = [&](int slot, int fb) {
#pragma unroll
        for (int kk = 0; kk < 2; ++kk) {
            const int cb = kk * 4 + g4;
            const int csw = (cb ^ sw) << 4;
#pragma unroll
            for (int m = 0; m < 4; ++m) {
                const int row = wr + m * 16 + rsel;
                af[fb][kk][m] = *(const short8*)((const char*)&sA[slot][0] + row * 128 + csw);
            }
#pragma unroll
            for (int n = 0; n < 4; ++n) {
                const int row = wc + n * 16 + rsel;
                bfr[fb][kk][n] = *(const short8*)((const char*)&sB[slot][0] + row * 128 + csw);
            }
        }
    };

    // prologue: stage slices 0,1; wait slice 0 landed; read its frags
    stage(0, 0);
    stage(1, 1);
    asm volatile("s_waitcnt vmcnt(8)" ::: "memory");
    __builtin_amdgcn_s_barrier();
    readfrags(0, 0);

#pragma unroll
    for (int s = 0; s < 16; ++s) {
        const int cur = s & 1;          // slot holding slice s; frag buffer for slice s
        const int nxt = cur ^ 1;

        // frag reads of slice s (issued last phase / prologue) complete
        asm volatile("s_waitcnt lgkmcnt(0)" ::: "memory");
        __builtin_amdgcn_sched_barrier(0);
        __builtin_amdgcn_s_barrier();        // B1: all waves done reading slot cur

        if (s + 2 < 16) stage(s + 2, cur);   // overwrite just-read slot

        if (docopy) {
            if (s > 0) xout[cbase + (size_t)(s - 1) * 262144] = creg;
            creg = xin[cbase + (size_t)s * 262144];
        }

        // counted waits: guarantee stage(s+1) landed; newer ops stay in flight
        if (docopy) {
            if (s == 0)       asm volatile("s_waitcnt vmcnt(9)"  ::: "memory");
            else if (s == 1)  asm volatile("s_waitcnt vmcnt(11)" ::: "memory");
            else if (s < 14)  asm volatile("s_waitcnt vmcnt(12)" ::: "memory");
            else if (s == 14) asm volatile("s_waitcnt vmcnt(4)"  ::: "memory");
        } else {
            if (s + 2 < 16)   asm volatile("s_waitcnt vmcnt(8)"  ::: "memory");
            else if (s == 14) asm volatile("s_waitcnt vmcnt(0)"  ::: "memory");
        }
        __builtin_amdgcn_s_barrier();        // B2: everyone's slice s+1 resident

        // issue next slice's frag reads — they complete at next phase's lgkmcnt
        if (s + 1 < 16) readfrags(nxt, nxt);

        // MFMA on already-resident F[cur]; overlaps the in-flight ds_reads & VMEM
        __builtin_amdgcn_s_setprio(1);
#pragma unroll
        for (int kk = 0; kk < 2; ++kk)
#pragma unroll
            for (int m = 0; m < 4; ++m)
#pragma unroll
                for (int n = 0; n < 4; ++n)
                    acc[m][n] = __builtin_amdgcn_mfma_f32_16x16x32_bf16(
                        af[cur][kk][m], bfr[cur][kk][n], acc[m][n], 0, 0, 0);
        __builtin_amdgcn_s_setprio(0);
    }

    if (docopy) xout[cbase + 15UL * 262144] = creg;

    // ---------------- epilogue (unchanged) ----------------
    const float scale = 1.0f / 2048.0f;
    const int r0 = (lane >> 4) * 4;
    const int c0 = lane & 15;

#pragma unroll
    for (int m = 0; m < 4; ++m)
#pragma unroll
        for (int n = 0; n < 4; ++n)
#pragma unroll
            for (int rr = 0; rr < 4; ++rr)
                acc[m][n][rr] = __expf(acc[m][n][rr] * scale);

#pragma unroll
    for (int m = 0; m < 4; ++m) {
#pragma unroll
        for (int n = 0; n < 4; ++n) {
            char* dbase = Sb + (size_t)(tr + wr + m * 16 + r0) * SROWB + 4096
                             + (size_t)(tc + wc + n * 16 + c0) * 2;
#pragma unroll
            for (int rr = 0; rr < 4; ++rr)
                *(_Float16*)(dbase + (size_t)rr * SROWB) = (_Float16)acc[m][n][rr];
        }
    }

#pragma unroll
    for (int m = 0; m < 4; ++m) {
#pragma unroll
        for (int rr = 0; rr < 4; ++rr) {
            float s = (acc[m][0][rr] + acc[m][1][rr]) + (acc[m][2][rr] + acc[m][3][rr]);
            s += __shfl_xor(s, 1, 64);
            s += __shfl_xor(s, 2, 64);
            s += __shfl_xor(s, 4, 64);
            s += __shfl_xor(s, 8, 64);
            if ((lane & 15) == 0) {
                char* prow = Sb + (size_t)(tr + wr + m * 16 + r0 + rr) * SROWB;
                ((float*)prow)[tj * 2 + (wid & 1)] = s;
            }
        }
    }

    if (ti != tj) {
#pragma unroll
        for (int m = 0; m < 4; ++m) {
#pragma unroll
            for (int n = 0; n < 4; ++n) {
                half4 h;
#pragma unroll
                for (int rr = 0; rr < 4; ++rr) h[rr] = (_Float16)acc[m][n][rr];
                char* mb = Sb + (size_t)(tc + wc + n * 16 + c0) * SROWB + 4096
                              + (size_t)(tr + wr + m * 16 + r0) * 2;
                *(half4*)mb = h;
            }
        }
#pragma unroll
        for (int n = 0; n < 4; ++n) {
            float s = 0.0f;
#pragma unroll
            for (int m = 0; m < 4; ++m)
#pragma unroll
                for (int rr = 0; rr < 4; ++rr) s += acc[m][n][rr];
            s += __shfl_xor(s, 16, 64);
            s += __shfl_xor(s, 32, 64);
            if (lane < 16) {
                char* prow = Sb + (size_t)(tc + wc + n * 16 + lane) * SROWB;
                ((float*)prow)[ti * 2 + (wid >> 1)] = s;
            }
        }
    }
}

// ---------- kernel 3: normalize each row in place ----------
__global__ __launch_bounds__(256) void normalize_rows(char* sc) {
    const int row  = blockIdx.x * 4 + (threadIdx.x >> 6);
    const int lane = threadIdx.x & 63;
    char* rowc = sc + (size_t)row * SROWB;
    const _Float16* e = (const _Float16*)(rowc + 4096);
    float* s = (float*)rowc;

    float p = (lane < PARTS) ? ((const float*)rowc)[lane] : 0.0f;
#pragma unroll
    for (int o = 32; o > 0; o >>= 1) p += __shfl_xor(p, o, 64);
    const float inv = 1.0f / p;

    half8 v[4];
#pragma unroll
    for (int c = 0; c < 4; ++c)
        v[c] = *(const half8*)(e + c * 512 + lane * 8);

#pragma unroll
    for (int c = 0; c < 4; ++c) {
        float4 f0, f1;
        f0.x = (float)v[c][0] * inv; f0.y = (float)v[c][1] * inv;
        f0.z = (float)v[c][2] * inv; f0.w = (float)v[c][3] * inv;
        f1.x = (float)v[c][4] * inv; f1.y = (float)v[c][5] * inv;
        f1.z = (float)v[c][6] * inv; f1.w = (float)v[c][7] * inv;
        *(float4*)(s + c * 512 + lane * 8)     = f0;
        *(float4*)(s + c * 512 + lane * 8 + 4) = f1;
    }
}

// ---------- launcher ----------
extern "C" void kernel_launch(void* const* d_in, const int* in_sizes, int n_in,
                              void* d_out, int out_size, void* d_ws, size_t ws_size,
                              hipStream_t stream) {
    const float* X = (const float*)d_in[0];
    float* out = (float*)d_out;
    char*  sc  = (char*)d_out + NIN * 4;

    cvt_packed<<<NIN / (256 * 8), 256, 0, stream>>>(X, sc);
    gemm_sym4<<<1088, 256, 0, stream>>>(sc, (const float4*)X, (float4*)out);
    normalize_rows<<<(B_ * S_) / 4, 256, 0, stream>>>(sc);
}

// Round 8
// 119.772 us; speedup vs baseline: 1.0128x; 1.0128x over previous
//
#include <hip/hip_runtime.h>

typedef unsigned short ushort_t;
using short8 = __attribute__((ext_vector_type(8))) short;
using half4  = __attribute__((ext_vector_type(4))) _Float16;
using half8  = __attribute__((ext_vector_type(8))) _Float16;
using f32x4  = __attribute__((ext_vector_type(4))) float;

#define AS1 __attribute__((address_space(1)))
#define AS3 __attribute__((address_space(3)))

// Problem sizes (fixed)
#define B_   8
#define S_   2048
#define D_   1024
#define NIN  (8UL * 2048UL * 1024UL)
#define PARTS 32
#define SROWB 8192UL
#define BATCHB (2048UL * SROWB)

// Per-score-row layout during the pipeline:
//   [0,128)     : 32 f32 partial row sums   (gemm -> normalize)
//   [2048,4096) : bf16 X row                (cvt -> gemm)
//   [4096,8192) : f16 E row = exp(logits)   (gemm -> normalize)
// normalize overwrites the whole row with final f32 scores.
// The exact f32 input copy streams through the gemm's idle VMEM slots.

// Super-tile order: the 16x16 upper triangle is walked in 4x4 supers so a
// generation's concurrent tiles share ~8 panels (2MB < 4MB XCD L2).
__constant__ int g_scum[11] = {0,10,26,42,58,68,84,100,110,126,136};
__constant__ int g_sTI[10]  = {0,0,0,0,1,1,1,2,2,3};
__constant__ int g_sTJ[10]  = {0,1,2,3,1,2,3,2,3,3};
__constant__ int g_di[10]   = {0,0,0,0,1,1,1,2,2,3};
__constant__ int g_dj[10]   = {0,1,2,3,1,2,3,2,3,3};

__device__ __forceinline__ ushort_t f2bf(float f) {
    unsigned u = __float_as_uint(f);
    u += 0x7FFFu + ((u >> 16) & 1u);
    return (ushort_t)(u >> 16);
}

// ---------- kernel 1: f32 X -> parked bf16 ----------
__global__ __launch_bounds__(256) void cvt_packed(const float* __restrict__ in,
                                                  char* sc) {
    size_t g = ((size_t)blockIdx.x * 256 + threadIdx.x) * 8;
    const float4* p = (const float4*)(in + g);
    float4 a = p[0], c = p[1];
    short8 r;
    r[0] = (short)f2bf(a.x); r[1] = (short)f2bf(a.y);
    r[2] = (short)f2bf(a.z); r[3] = (short)f2bf(a.w);
    r[4] = (short)f2bf(c.x); r[5] = (short)f2bf(c.y);
    r[6] = (short)f2bf(c.z); r[7] = (short)f2bf(c.w);
    size_t xrow = g >> 10;
    size_t col  = g & 1023;
    char* dst = sc + xrow * SROWB + 2048 + col * 2;
    *(short8*)dst = r;
}

// ---------- kernel 2: symmetric GEMM (R6 schedule) + super-tile order ----------
__global__ __launch_bounds__(256, 2) void gemm_sym5(char* sc,
                                                    const float4* xin,
                                                    float4* xout) {
    __shared__ __align__(16) ushort_t sA[2][128 * 64];
    __shared__ __align__(16) ushort_t sB[2][128 * 64];

    const int lin = blockIdx.x;
    // bijective XCD swizzle: 1088 = 8 * 136; XCD x walks batch x in super order
    const int wg  = (lin & 7) * 136 + (lin >> 3);
    const int b   = wg / 136;
    int rem = wg % 136;

    // decode rem -> (ti, tj) via super-tile order
    int sp = 0;
    while (rem >= g_scum[sp + 1]) ++sp;
    const int w = rem - g_scum[sp];
    int ti, tj;
    if (g_sTI[sp] == g_sTJ[sp]) {
        ti = g_sTI[sp] * 4 + g_di[w];
        tj = g_sTJ[sp] * 4 + g_dj[w];
    } else {
        ti = g_sTI[sp] * 4 + (w >> 2);
        tj = g_sTJ[sp] * 4 + (w & 3);
    }
    const int tr = ti * 128, tc = tj * 128;

    char* Sb = sc + (size_t)b * BATCHB;

    const int tid  = threadIdx.x;
    const int lane = tid & 63;
    const int wid  = tid >> 6;
    const int wr = (wid >> 1) * 64;
    const int wc = (wid & 1) * 64;

    const bool docopy = (lin < 1024);
    const size_t cbase = (size_t)lin * 256 + tid;

    f32x4 acc[4][4] = {};
    float4 creg;

    const int srow_s = tid >> 3;
    const int cd     = tid & 7;
    const int rsel = lane & 15;
    const int g4   = lane >> 4;
    const int sw   = lane & 7;

    auto stage = [&](int s, int slot) {
#pragma unroll
        for (int j = 0; j < 4; ++j) {
            const int row = j * 32 + srow_s;
            const int csw = (cd ^ (row & 7)) << 4;
            const size_t rbA = (size_t)(tr + row) * SROWB + 2048 + (size_t)s * 128;
            const size_t rbB = (size_t)(tc + row) * SROWB + 2048 + (size_t)s * 128;
            __builtin_amdgcn_global_load_lds((const AS1 void*)(Sb + rbA + csw),
                (AS3 void*)((char*)&sA[slot][0] + j * 4096 + tid * 16), 16, 0, 0);
            __builtin_amdgcn_global_load_lds((const AS1 void*)(Sb + rbB + csw),
                (AS3 void*)((char*)&sB[slot][0] + j * 4096 + tid * 16), 16, 0, 0);
        }
    };

    // prologue
    stage(0, 0);
    stage(1, 1);
    asm volatile("s_waitcnt vmcnt(8)" ::: "memory");
    __builtin_amdgcn_s_barrier();

#pragma unroll
    for (int s = 0; s < 16; ++s) {
        const int slot = s & 1;

        short8 af[2][4], bfr[2][4];
#pragma unroll
        for (int kk = 0; kk < 2; ++kk) {
            const int cb = kk * 4 + g4;
            const int csw = (cb ^ sw) << 4;
#pragma unroll
            for (int m = 0; m < 4; ++m) {
                const int row = wr + m * 16 + rsel;
                af[kk][m] = *(const short8*)((const char*)&sA[slot][0] + row * 128 + csw);
            }
#pragma unroll
            for (int n = 0; n < 4; ++n) {
                const int row = wc + n * 16 + rsel;
                bfr[kk][n] = *(const short8*)((const char*)&sB[slot][0] + row * 128 + csw);
            }
        }
        asm volatile("s_waitcnt lgkmcnt(0)" ::: "memory");
        __builtin_amdgcn_s_barrier();        // B1: reads of slice s done everywhere

        if (s + 2 < 16) stage(s + 2, slot);  // overwrite just-read slot

        if (docopy) {
            if (s > 0) xout[cbase + (size_t)(s - 1) * 262144] = creg;
            creg = xin[cbase + (size_t)s * 262144];
        }

        // counted waits: guarantee stage(s+1) landed; newer ops stay in flight
        if (docopy) {
            if (s == 0)       asm volatile("s_waitcnt vmcnt(9)"  ::: "memory");
            else if (s == 1)  asm volatile("s_waitcnt vmcnt(11)" ::: "memory");
            else if (s < 14)  asm volatile("s_waitcnt vmcnt(12)" ::: "memory");
            else if (s == 14) asm volatile("s_waitcnt vmcnt(4)"  ::: "memory");
        } else {
            if (s + 2 < 16)   asm volatile("s_waitcnt vmcnt(8)"  ::: "memory");
            else if (s == 14) asm volatile("s_waitcnt vmcnt(0)"  ::: "memory");
        }
        __builtin_amdgcn_s_barrier();        // B2: everyone's slice s+1 resident

        __builtin_amdgcn_s_setprio(1);
#pragma unroll
        for (int kk = 0; kk < 2; ++kk)
#pragma unroll
            for (int m = 0; m < 4; ++m)
#pragma unroll
                for (int n = 0; n < 4; ++n)
                    acc[m][n] = __builtin_amdgcn_mfma_f32_16x16x32_bf16(
                        af[kk][m], bfr[kk][n], acc[m][n], 0, 0, 0);
        __builtin_amdgcn_s_setprio(0);
    }

    if (docopy) xout[cbase + 15UL * 262144] = creg;

    // ---------------- epilogue (unchanged) ----------------
    const float scale = 1.0f / 2048.0f;
    const int r0 = (lane >> 4) * 4;
    const int c0 = lane & 15;

#pragma unroll
    for (int m = 0; m < 4; ++m)
#pragma unroll
        for (int n = 0; n < 4; ++n)
#pragma unroll
            for (int rr = 0; rr < 4; ++rr)
                acc[m][n][rr] = __expf(acc[m][n][rr] * scale);

#pragma unroll
    for (int m = 0; m < 4; ++m) {
#pragma unroll
        for (int n = 0; n < 4; ++n) {
            char* dbase = Sb + (size_t)(tr + wr + m * 16 + r0) * SROWB + 4096
                             + (size_t)(tc + wc + n * 16 + c0) * 2;
#pragma unroll
            for (int rr = 0; rr < 4; ++rr)
                *(_Float16*)(dbase + (size_t)rr * SROWB) = (_Float16)acc[m][n][rr];
        }
    }

#pragma unroll
    for (int m = 0; m < 4; ++m) {
#pragma unroll
        for (int rr = 0; rr < 4; ++rr) {
            float s = (acc[m][0][rr] + acc[m][1][rr]) + (acc[m][2][rr] + acc[m][3][rr]);
            s += __shfl_xor(s, 1, 64);
            s += __shfl_xor(s, 2, 64);
            s += __shfl_xor(s, 4, 64);
            s += __shfl_xor(s, 8, 64);
            if ((lane & 15) == 0) {
                char* prow = Sb + (size_t)(tr + wr + m * 16 + r0 + rr) * SROWB;
                ((float*)prow)[tj * 2 + (wid & 1)] = s;
            }
        }
    }

    if (ti != tj) {
#pragma unroll
        for (int m = 0; m < 4; ++m) {
#pragma unroll
            for (int n = 0; n < 4; ++n) {
                half4 h;
#pragma unroll
                for (int rr = 0; rr < 4; ++rr) h[rr] = (_Float16)acc[m][n][rr];
                char* mb = Sb + (size_t)(tc + wc + n * 16 + c0) * SROWB + 4096
                              + (size_t)(tr + wr + m * 16 + r0) * 2;
                *(half4*)mb = h;
            }
        }
#pragma unroll
        for (int n = 0; n < 4; ++n) {
            float s = 0.0f;
#pragma unroll
            for (int m = 0; m < 4; ++m)
#pragma unroll
                for (int rr = 0; rr < 4; ++rr) s += acc[m][n][rr];
            s += __shfl_xor(s, 16, 64);
            s += __shfl_xor(s, 32, 64);
            if (lane < 16) {
                char* prow = Sb + (size_t)(tc + wc + n * 16 + lane) * SROWB;
                ((float*)prow)[ti * 2 + (wid >> 1)] = s;
            }
        }
    }
}

// ---------- kernel 3: normalize each row in place ----------
__global__ __launch_bounds__(256) void normalize_rows(char* sc) {
    const int row  = blockIdx.x * 4 + (threadIdx.x >> 6);
    const int lane = threadIdx.x & 63;
    char* rowc = sc + (size_t)row * SROWB;
    const _Float16* e = (const _Float16*)(rowc + 4096);
    float* s = (float*)rowc;

    float p = (lane < PARTS) ? ((const float*)rowc)[lane] : 0.0f;
#pragma unroll
    for (int o = 32; o > 0; o >>= 1) p += __shfl_xor(p, o, 64);
    const float inv = 1.0f / p;

    half8 v[4];
#pragma unroll
    for (int c = 0; c < 4; ++c)
        v[c] = *(const half8*)(e + c * 512 + lane * 8);

#pragma unroll
    for (int c = 0; c < 4; ++c) {
        float4 f0, f1;
        f0.x = (float)v[c][0] * inv; f0.y = (float)v[c][1] * inv;
        f0.z = (float)v[c][2] * inv; f0.w = (float)v[c][3] * inv;
        f1.x = (float)v[c][4] * inv; f1.y = (float)v[c][5] * inv;
        f1.z = (float)v[c][6] * inv; f1.w = (float)v[c][7] * inv;
        *(float4*)(s + c * 512 + lane * 8)     = f0;
        *(float4*)(s + c * 512 + lane * 8 + 4) = f1;
    }
}

// ---------- launcher ----------
extern "C" void kernel_launch(void* const* d_in, const int* in_sizes, int n_in,
                              void* d_out, int out_size, void* d_ws, size_t ws_size,
                              hipStream_t stream) {
    const float* X = (const float*)d_in[0];
    float* out = (float*)d_out;
    char*  sc  = (char*)d_out + NIN * 4;

    cvt_packed<<<NIN / (256 * 8), 256, 0, stream>>>(X, sc);
    gemm_sym5<<<1088, 256, 0, stream>>>(sc, (const float4*)X, (float4*)out);
    normalize_rows<<<(B_ * S_) / 4, 256, 0, stream>>>(sc);
}